// Round 1
// baseline (60.594 us; speedup 1.0000x reference)
//
#include <hip/hip_runtime.h>

#define C_NUM   256
#define K_CODES 4096
#define D_CB    8
#define TUPLES  128          // B*N = 8*16
#define THREADS 512
#define WAVES   8
#define CODES_PER_WAVE (K_CODES / WAVES)   // 512

__global__ __launch_bounds__(THREADS)
void dkvb_kernel(const float* __restrict__ emb,
                 const float* __restrict__ keys,
                 const float* __restrict__ values,
                 float* __restrict__ out) {
    extern __shared__ float smem[];
    float* k_lds  = smem;                      // [4096 * 8]  = 128 KB
    float* k2_lds = smem + K_CODES * D_CB;     // [4096]      =  16 KB

    const int c    = blockIdx.x;
    const int tid  = threadIdx.x;
    const int wave = tid >> 6;
    const int lane = tid & 63;

    // ---- stage keys[c] (128 KB) into LDS, linear float4 copy ----
    const float4* ksrc = (const float4*)(keys + (size_t)c * K_CODES * D_CB);
    float4* kdst = (float4*)k_lds;
    #pragma unroll
    for (int it = 0; it < 16; ++it) {
        kdst[it * THREADS + tid] = ksrc[it * THREADS + tid];
    }
    __syncthreads();

    // ---- precompute ||k||^2 per code (8 codes per thread) ----
    #pragma unroll
    for (int it = 0; it < 8; ++it) {
        const int k = it * THREADS + tid;
        const float* row = &k_lds[k * D_CB];
        float s = row[0] * row[0];
        #pragma unroll
        for (int j = 1; j < 8; ++j) s = fmaf(row[j], row[j], s);
        k2_lds[k] = s;
    }

    // ---- load x for this lane's two tuples (tA = lane, tB = lane+64) ----
    // x[b,n,c,j] = emb[(b*2048 + c*8 + j)*16 + n]
    const int tA = lane, tB = lane + 64;
    const int bA = tA >> 4, nA = tA & 15;
    const int bB = tB >> 4, nB = tB & 15;
    const float* ea = emb + ((size_t)bA * 2048 + c * 8) * 16 + nA;
    const float* eb = emb + ((size_t)bB * 2048 + c * 8) * 16 + nB;
    float xA[8], xB[8];
    #pragma unroll
    for (int j = 0; j < 8; ++j) { xA[j] = ea[j * 16]; xB[j] = eb[j * 16]; }
    float x2A = xA[0] * xA[0];
    float x2B = xB[0] * xB[0];
    #pragma unroll
    for (int j = 1; j < 8; ++j) {
        x2A = fmaf(xA[j], xA[j], x2A);
        x2B = fmaf(xB[j], xB[j], x2B);
    }

    __syncthreads();   // k2_lds ready

    // ---- main scan: this wave owns codes [wave*512, wave*512+512) ----
    float bestA = 3.4028235e38f, bestB = 3.4028235e38f;
    int   idxA = 0, idxB = 0;
    const int k0 = wave * CODES_PER_WAVE;
    for (int kk = 0; kk < CODES_PER_WAVE; kk += 4) {
        const int k = k0 + kk;
        const float4 q2 = *(const float4*)&k2_lds[k];   // 4 codes' ||k||^2
        #pragma unroll
        for (int u = 0; u < 4; ++u) {
            const float4 r0 = *(const float4*)&k_lds[(k + u) * 8];
            const float4 r1 = *(const float4*)&k_lds[(k + u) * 8 + 4];
            const float k2v = (u == 0) ? q2.x : (u == 1) ? q2.y : (u == 2) ? q2.z : q2.w;

            float dA = xA[0] * r0.x;
            dA = fmaf(xA[1], r0.y, dA);
            dA = fmaf(xA[2], r0.z, dA);
            dA = fmaf(xA[3], r0.w, dA);
            dA = fmaf(xA[4], r1.x, dA);
            dA = fmaf(xA[5], r1.y, dA);
            dA = fmaf(xA[6], r1.z, dA);
            dA = fmaf(xA[7], r1.w, dA);
            const float distA = fmaf(dA, -2.0f, x2A + k2v);

            float dB = xB[0] * r0.x;
            dB = fmaf(xB[1], r0.y, dB);
            dB = fmaf(xB[2], r0.z, dB);
            dB = fmaf(xB[3], r0.w, dB);
            dB = fmaf(xB[4], r1.x, dB);
            dB = fmaf(xB[5], r1.y, dB);
            dB = fmaf(xB[6], r1.z, dB);
            dB = fmaf(xB[7], r1.w, dB);
            const float distB = fmaf(dB, -2.0f, x2B + k2v);

            const bool ltA = distA < bestA;
            bestA = ltA ? distA : bestA;
            idxA  = ltA ? (k + u) : idxA;
            const bool ltB = distB < bestB;
            bestB = ltB ? distB : bestB;
            idxB  = ltB ? (k + u) : idxB;
        }
    }

    // ---- cross-wave argmin combine via LDS (reuse k_lds space) ----
    __syncthreads();   // all waves done scanning before overwriting k_lds
    float* rv = smem;                 // [8][128] best values (4 KB)
    int*   ri = (int*)(smem + 1024);  // [8][128] best indices (4 KB)
    rv[wave * TUPLES + tA] = bestA;  ri[wave * TUPLES + tA] = idxA;
    rv[wave * TUPLES + tB] = bestB;  ri[wave * TUPLES + tB] = idxB;
    __syncthreads();

    if (tid < TUPLES) {
        float best = rv[tid];
        int   idx  = ri[tid];
        #pragma unroll
        for (int w = 1; w < WAVES; ++w) {       // ascending wave order = ascending
            const float v = rv[w * TUPLES + tid];   // code ranges -> numpy tie-break
            const int   i = ri[w * TUPLES + tid];
            if (v < best) { best = v; idx = i; }
        }
        const int b = tid >> 4, n = tid & 15;
        const float* vr = values + ((size_t)c * K_CODES + idx) * D_CB;
        float* op = out + ((size_t)b * 2048 + c * 8) * 16 + n;
        #pragma unroll
        for (int j = 0; j < 8; ++j) op[j * 16] = vr[j];
    }
}

extern "C" void kernel_launch(void* const* d_in, const int* in_sizes, int n_in,
                              void* d_out, int out_size, void* d_ws, size_t ws_size,
                              hipStream_t stream) {
    const float* emb    = (const float*)d_in[0];
    const float* keys   = (const float*)d_in[1];
    const float* values = (const float*)d_in[2];
    float* out = (float*)d_out;

    const size_t smem_bytes = (size_t)(K_CODES * D_CB + K_CODES) * sizeof(float); // 147456
    hipFuncSetAttribute((const void*)dkvb_kernel,
                        hipFuncAttributeMaxDynamicSharedMemorySize, (int)smem_bytes);
    dkvb_kernel<<<C_NUM, THREADS, smem_bytes, stream>>>(emb, keys, values, out);
}

// Round 2
// 50.328 us; speedup vs baseline: 1.2040x; 1.2040x over previous
//
#include <hip/hip_runtime.h>

#define C_NUM   256
#define K_CODES 4096
#define D_CB    8
#define THREADS 512
#define WAVES   8
#define TPW     16                 // tuples per wave (128 tuples / 8 waves)
#define CHUNKS  (K_CODES / 64)     // 64 codes (one per lane) per chunk

__global__ __launch_bounds__(THREADS, 2)
void dkvb_kernel(const float* __restrict__ emb,
                 const float* __restrict__ keys,
                 const float* __restrict__ values,
                 float* __restrict__ out) {
    __shared__ float xs[128][D_CB];   // 4 KB

    const int c    = blockIdx.x;
    const int tid  = threadIdx.x;
    const int wave = tid >> 6;
    const int lane = tid & 63;

    // ---- stage x for this codebook into LDS ----
    // x[t][j] = emb[(t>>4)*32768 + c*128 + j*16 + (t&15)],  t = b*16+n
    {
        int e = tid;
        #pragma unroll
        for (int r = 0; r < 2; ++r, e += THREADS) {
            const int t = e >> 3, j = e & 7;
            xs[t][j] = emb[(size_t)(t >> 4) * 32768 + c * 128 + j * 16 + (t & 15)];
        }
    }
    __syncthreads();

    // ---- wave-uniform x + x2 in VGPRs (bitwise-identical chain to R1) ----
    float x[TPW][8];
    float x2[TPW];
    #pragma unroll
    for (int t = 0; t < TPW; ++t) {
        #pragma unroll
        for (int j = 0; j < 8; ++j) x[t][j] = xs[wave * TPW + t][j];
        float s = x[t][0] * x[t][0];
        #pragma unroll
        for (int j = 1; j < 8; ++j) s = fmaf(x[t][j], x[t][j], s);
        x2[t] = s;
    }

    float bestd[TPW];
    int   besti[TPW];
    #pragma unroll
    for (int t = 0; t < TPW; ++t) { bestd[t] = 3.4028235e38f; besti[t] = 0; }

    // ---- scan all 4096 codes; lane l owns codes {l, 64+l, 128+l, ...} ----
    const float4* kb = (const float4*)(keys + (size_t)c * K_CODES * D_CB);
    float4 a0 = kb[lane * 2];
    float4 a1 = kb[lane * 2 + 1];
    for (int ch = 0; ch < CHUNKS; ++ch) {
        // prefetch next chunk (clamped on last iter; harmless re-read)
        const int nc = (ch + 1 < CHUNKS) ? (ch + 1) : ch;
        const float4 b0 = kb[nc * 128 + lane * 2];
        const float4 b1 = kb[nc * 128 + lane * 2 + 1];

        const int code = ch * 64 + lane;
        float k2 = a0.x * a0.x;
        k2 = fmaf(a0.y, a0.y, k2);
        k2 = fmaf(a0.z, a0.z, k2);
        k2 = fmaf(a0.w, a0.w, k2);
        k2 = fmaf(a1.x, a1.x, k2);
        k2 = fmaf(a1.y, a1.y, k2);
        k2 = fmaf(a1.z, a1.z, k2);
        k2 = fmaf(a1.w, a1.w, k2);

        #pragma unroll
        for (int t = 0; t < TPW; ++t) {
            float d = x[t][0] * a0.x;
            d = fmaf(x[t][1], a0.y, d);
            d = fmaf(x[t][2], a0.z, d);
            d = fmaf(x[t][3], a0.w, d);
            d = fmaf(x[t][4], a1.x, d);
            d = fmaf(x[t][5], a1.y, d);
            d = fmaf(x[t][6], a1.z, d);
            d = fmaf(x[t][7], a1.w, d);
            const float dist = fmaf(d, -2.0f, x2[t] + k2);
            const bool lt = dist < bestd[t];
            bestd[t] = lt ? dist : bestd[t];
            besti[t] = lt ? code : besti[t];
        }
        a0 = b0; a1 = b1;
    }

    // ---- cross-lane argmin per tuple (tie -> smaller index == numpy) ----
    int myidx = 0;
    #pragma unroll
    for (int t = 0; t < TPW; ++t) {
        float d = bestd[t];
        int   i = besti[t];
        #pragma unroll
        for (int m = 32; m >= 1; m >>= 1) {
            const float od = __shfl_xor(d, m, 64);
            const int   oi = __shfl_xor(i, m, 64);
            if (od < d || (od == d && oi < i)) { d = od; i = oi; }
        }
        if (lane == t) myidx = i;
    }

    // ---- gather values row + scatter to output ----
    if (lane < TPW) {
        const int tg = wave * TPW + lane;        // tuple = b*16 + n
        const int b = tg >> 4, n = tg & 15;
        const float4* vr = (const float4*)(values + ((size_t)c * K_CODES + myidx) * D_CB);
        const float4 v0 = vr[0];
        const float4 v1 = vr[1];
        float* op = out + (size_t)b * 32768 + c * 128 + n;
        op[0]   = v0.x; op[16]  = v0.y; op[32]  = v0.z; op[48]  = v0.w;
        op[64]  = v1.x; op[80]  = v1.y; op[96]  = v1.z; op[112] = v1.w;
    }
}

extern "C" void kernel_launch(void* const* d_in, const int* in_sizes, int n_in,
                              void* d_out, int out_size, void* d_ws, size_t ws_size,
                              hipStream_t stream) {
    const float* emb    = (const float*)d_in[0];
    const float* keys   = (const float*)d_in[1];
    const float* values = (const float*)d_in[2];
    float* out = (float*)d_out;
    dkvb_kernel<<<C_NUM, THREADS, 0, stream>>>(emb, keys, values, out);
}